// Round 1
// baseline (2690.894 us; speedup 1.0000x reference)
//
#include <hip/hip_runtime.h>
#include <math.h>

#define THREADS 256

constexpr int Bc = 4, Tt = 2048, Dd = 768, Hh = 12, Hd = 64, Df = 3072;
constexpr int BT = Bc * Tt;  // 8192 rows

__device__ inline float waveMax(float v) {
#pragma unroll
  for (int o = 32; o; o >>= 1) v = fmaxf(v, __shfl_xor(v, o));
  return v;
}
__device__ inline float waveSum(float v) {
#pragma unroll
  for (int o = 32; o; o >>= 1) v += __shfl_xor(v, o);
  return v;
}

__device__ inline float gelu_exact(float g) {
  return 0.5f * g * (1.0f + erff(g * 0.70710678118654752440f));
}

// ---------------------------------------------------------------------------
// Generic 128x128 fp32 tiled GEMM over M=8192 rows.
// MODE 0: C = A@B + bias, written to split-head QKV layout [B,H,T,HD]
// MODE 1: A = ctx gathered from [B,H,T,HD]; C = add + A@B + bias (row-major)
// MODE 2: C = gelu(A@B + bias) (row-major)
// MODE 3: C = add + A@B + bias (row-major)
// ---------------------------------------------------------------------------
template <int MODE>
__global__ __launch_bounds__(THREADS) void gemm128(
    const float* __restrict__ A, const float* __restrict__ B,
    const float* __restrict__ bias, const float* __restrict__ add,
    float* __restrict__ C, int K, int N) {
  __shared__ float As[16][136];
  __shared__ float Bs[16][136];
  const int tid = threadIdx.x;
  const int tx = tid & 15, ty = tid >> 4;
  const int m0 = blockIdx.y * 128, n0 = blockIdx.x * 128;

  float acc[8][8];
#pragma unroll
  for (int i = 0; i < 8; i++)
#pragma unroll
    for (int j = 0; j < 8; j++) acc[i][j] = 0.f;

  for (int k0 = 0; k0 < K; k0 += 16) {
    // ---- stage A tile (transposed to As[k][m]) ----
#pragma unroll
    for (int w = 0; w < 2; ++w) {
      int f = tid + w * 256;
      int r = f >> 2, c4 = f & 3;
      int kk = k0 + c4 * 4;
      const float* src;
      if constexpr (MODE == 1) {
        int m = m0 + r;
        int b = m >> 11, t = m & 2047;
        int head = kk >> 6, d = kk & 63;
        src = &A[((size_t)((b * Hh + head) * Tt + t) << 6) + d];
      } else {
        src = &A[(size_t)(m0 + r) * K + kk];
      }
      float4 av = *(const float4*)src;
      As[c4 * 4 + 0][r] = av.x;
      As[c4 * 4 + 1][r] = av.y;
      As[c4 * 4 + 2][r] = av.z;
      As[c4 * 4 + 3][r] = av.w;
    }
    // ---- stage B tile ----
#pragma unroll
    for (int w = 0; w < 2; ++w) {
      int f = tid + w * 256;
      int kr = f >> 5, nc = f & 31;
      float4 bv = *(const float4*)&B[(size_t)(k0 + kr) * N + n0 + nc * 4];
      *(float4*)&Bs[kr][nc * 4] = bv;
    }
    __syncthreads();
#pragma unroll
    for (int kk = 0; kk < 16; ++kk) {
      float4 a0 = *(const float4*)&As[kk][ty * 4];
      float4 a1 = *(const float4*)&As[kk][ty * 4 + 64];
      float4 b0 = *(const float4*)&Bs[kk][tx * 4];
      float4 b1 = *(const float4*)&Bs[kk][tx * 4 + 64];
      float a[8] = {a0.x, a0.y, a0.z, a0.w, a1.x, a1.y, a1.z, a1.w};
      float b[8] = {b0.x, b0.y, b0.z, b0.w, b1.x, b1.y, b1.z, b1.w};
#pragma unroll
      for (int i = 0; i < 8; i++)
#pragma unroll
        for (int j = 0; j < 8; j++) acc[i][j] = fmaf(a[i], b[j], acc[i][j]);
    }
    __syncthreads();
  }

  // ---- epilogue ----
#pragma unroll
  for (int i = 0; i < 8; i++) {
    int m = m0 + ((i < 4) ? (ty * 4 + i) : (64 + ty * 4 + i - 4));
#pragma unroll
    for (int jh = 0; jh < 2; ++jh) {
      int n = n0 + jh * 64 + tx * 4;
      float vals[4];
#pragma unroll
      for (int j = 0; j < 4; j++) {
        float g = acc[i][jh * 4 + j] + bias[n + j];
        if constexpr (MODE == 1 || MODE == 3) g += add[(size_t)m * Dd + n + j];
        if constexpr (MODE == 2) g = gelu_exact(g);
        vals[j] = g;
      }
      float4 v = make_float4(vals[0], vals[1], vals[2], vals[3]);
      if constexpr (MODE == 0) {
        int b = m >> 11, t = m & 2047;
        int head = n >> 6, d = n & 63;
        *(float4*)&C[((size_t)((b * Hh + head) * Tt + t) << 6) + d] = v;
      } else {
        *(float4*)&C[(size_t)m * N + n] = v;
      }
    }
  }
}

// ---------------------------------------------------------------------------
// scores = scale * Q @ K^T per (b,h); mask==0 -> -inf.  Both [2048,64] row-major.
// ---------------------------------------------------------------------------
__global__ __launch_bounds__(THREADS) void scores_nt(
    const float* __restrict__ Q, const float* __restrict__ Kmat,
    const int* __restrict__ mask, float* __restrict__ attn) {
  const int bh = blockIdx.z;
  const float* Qb = Q + (size_t)bh * Tt * Hd;
  const float* Kb = Kmat + (size_t)bh * Tt * Hd;
  float* Cb = attn + (size_t)bh * Tt * Tt;
  const int b = bh / Hh;

  __shared__ float As[16][136];
  __shared__ float Bs[16][136];
  const int tid = threadIdx.x;
  const int tx = tid & 15, ty = tid >> 4;
  const int m0 = blockIdx.y * 128, n0 = blockIdx.x * 128;

  float acc[8][8];
#pragma unroll
  for (int i = 0; i < 8; i++)
#pragma unroll
    for (int j = 0; j < 8; j++) acc[i][j] = 0.f;

#pragma unroll
  for (int k0 = 0; k0 < Hd; k0 += 16) {
#pragma unroll
    for (int w = 0; w < 2; ++w) {
      int f = tid + w * 256;
      int r = f >> 2, c4 = f & 3;
      float4 av = *(const float4*)&Qb[(size_t)(m0 + r) * Hd + k0 + c4 * 4];
      As[c4 * 4 + 0][r] = av.x;
      As[c4 * 4 + 1][r] = av.y;
      As[c4 * 4 + 2][r] = av.z;
      As[c4 * 4 + 3][r] = av.w;
    }
#pragma unroll
    for (int w = 0; w < 2; ++w) {
      int f = tid + w * 256;
      int r = f >> 2, c4 = f & 3;
      float4 bv = *(const float4*)&Kb[(size_t)(n0 + r) * Hd + k0 + c4 * 4];
      Bs[c4 * 4 + 0][r] = bv.x;
      Bs[c4 * 4 + 1][r] = bv.y;
      Bs[c4 * 4 + 2][r] = bv.z;
      Bs[c4 * 4 + 3][r] = bv.w;
    }
    __syncthreads();
#pragma unroll
    for (int kk = 0; kk < 16; ++kk) {
      float4 a0 = *(const float4*)&As[kk][ty * 4];
      float4 a1 = *(const float4*)&As[kk][ty * 4 + 64];
      float4 b0 = *(const float4*)&Bs[kk][tx * 4];
      float4 b1 = *(const float4*)&Bs[kk][tx * 4 + 64];
      float a[8] = {a0.x, a0.y, a0.z, a0.w, a1.x, a1.y, a1.z, a1.w};
      float b[8] = {b0.x, b0.y, b0.z, b0.w, b1.x, b1.y, b1.z, b1.w};
#pragma unroll
      for (int i = 0; i < 8; i++)
#pragma unroll
        for (int j = 0; j < 8; j++) acc[i][j] = fmaf(a[i], b[j], acc[i][j]);
    }
    __syncthreads();
  }

  const float scale = 0.125f;  // 1/sqrt(64)
#pragma unroll
  for (int i = 0; i < 8; i++) {
    int m = m0 + ((i < 4) ? (ty * 4 + i) : (64 + ty * 4 + i - 4));
#pragma unroll
    for (int jh = 0; jh < 2; ++jh) {
      int n = n0 + jh * 64 + tx * 4;
      float vals[4];
#pragma unroll
      for (int j = 0; j < 4; j++) {
        float g = acc[i][jh * 4 + j] * scale;
        if (mask[b * Tt + n + j] == 0) g = -INFINITY;
        vals[j] = g;
      }
      *(float4*)&Cb[(size_t)m * Tt + n] =
          make_float4(vals[0], vals[1], vals[2], vals[3]);
    }
  }
}

// ---------------------------------------------------------------------------
// Row softmax over 2048 entries, in place.  One block per row.
// ---------------------------------------------------------------------------
__global__ __launch_bounds__(THREADS) void softmax_rows(float* __restrict__ attn) {
  float* p = attn + (size_t)blockIdx.x * Tt;
  const int tid = threadIdx.x;

  float4 v0 = ((float4*)p)[tid];
  float4 v1 = ((float4*)p)[tid + 256];
  float x[8] = {v0.x, v0.y, v0.z, v0.w, v1.x, v1.y, v1.z, v1.w};

  float tmax = x[0];
#pragma unroll
  for (int i = 1; i < 8; i++) tmax = fmaxf(tmax, x[i]);
  tmax = waveMax(tmax);
  __shared__ float redm[4];
  if ((tid & 63) == 0) redm[tid >> 6] = tmax;
  __syncthreads();
  float bm = fmaxf(fmaxf(redm[0], redm[1]), fmaxf(redm[2], redm[3]));

  float tsum = 0.f;
#pragma unroll
  for (int i = 0; i < 8; i++) {
    x[i] = __expf(x[i] - bm);
    tsum += x[i];
  }
  tsum = waveSum(tsum);
  __shared__ float reds[4];
  if ((tid & 63) == 0) reds[tid >> 6] = tsum;
  __syncthreads();
  float bs = reds[0] + reds[1] + reds[2] + reds[3];
  float inv = 1.0f / bs;

  ((float4*)p)[tid] = make_float4(x[0] * inv, x[1] * inv, x[2] * inv, x[3] * inv);
  ((float4*)p)[tid + 256] =
      make_float4(x[4] * inv, x[5] * inv, x[6] * inv, x[7] * inv);
}

// ---------------------------------------------------------------------------
// ctx = attn @ V per (b,h).  attn [2048,2048], V [2048,64] -> ctx [2048,64]
// ---------------------------------------------------------------------------
__global__ __launch_bounds__(THREADS) void ctx_gemm(
    const float* __restrict__ attn, const float* __restrict__ V,
    float* __restrict__ ctx) {
  const int bh = blockIdx.z;
  const float* Ab = attn + (size_t)bh * Tt * Tt;
  const float* Vb = V + (size_t)bh * Tt * Hd;
  float* Cb = ctx + (size_t)bh * Tt * Hd;

  __shared__ float As[32][136];
  __shared__ float Bs[32][72];
  const int tid = threadIdx.x;
  const int tx = tid & 15, ty = tid >> 4;
  const int m0 = blockIdx.y * 128;

  float acc[8][4];
#pragma unroll
  for (int i = 0; i < 8; i++)
#pragma unroll
    for (int j = 0; j < 4; j++) acc[i][j] = 0.f;

  for (int k0 = 0; k0 < Tt; k0 += 32) {
#pragma unroll
    for (int w = 0; w < 4; ++w) {
      int f = tid + w * 256;
      int r = f >> 3, c8 = f & 7;
      float4 av = *(const float4*)&Ab[(size_t)(m0 + r) * Tt + k0 + c8 * 4];
      As[c8 * 4 + 0][r] = av.x;
      As[c8 * 4 + 1][r] = av.y;
      As[c8 * 4 + 2][r] = av.z;
      As[c8 * 4 + 3][r] = av.w;
    }
#pragma unroll
    for (int w = 0; w < 2; ++w) {
      int f = tid + w * 256;
      int kr = f >> 4, nc = f & 15;
      float4 bv = *(const float4*)&Vb[(size_t)(k0 + kr) * Hd + nc * 4];
      *(float4*)&Bs[kr][nc * 4] = bv;
    }
    __syncthreads();
#pragma unroll
    for (int kk = 0; kk < 32; ++kk) {
      float4 a0 = *(const float4*)&As[kk][ty * 4];
      float4 a1 = *(const float4*)&As[kk][ty * 4 + 64];
      float4 b0 = *(const float4*)&Bs[kk][tx * 4];
      float a[8] = {a0.x, a0.y, a0.z, a0.w, a1.x, a1.y, a1.z, a1.w};
      float b[4] = {b0.x, b0.y, b0.z, b0.w};
#pragma unroll
      for (int i = 0; i < 8; i++)
#pragma unroll
        for (int j = 0; j < 4; j++) acc[i][j] = fmaf(a[i], b[j], acc[i][j]);
    }
    __syncthreads();
  }

#pragma unroll
  for (int i = 0; i < 8; i++) {
    int m = m0 + ((i < 4) ? (ty * 4 + i) : (64 + ty * 4 + i - 4));
    *(float4*)&Cb[(size_t)m * Hd + tx * 4] =
        make_float4(acc[i][0], acc[i][1], acc[i][2], acc[i][3]);
  }
}

// ---------------------------------------------------------------------------
extern "C" void kernel_launch(void* const* d_in, const int* in_sizes, int n_in,
                              void* d_out, int out_size, void* d_ws,
                              size_t ws_size, hipStream_t stream) {
  const float* x = (const float*)d_in[0];
  const int* mask = (const int*)d_in[1];
  const float* Wq = (const float*)d_in[2];
  const float* bq = (const float*)d_in[3];
  const float* Wk = (const float*)d_in[4];
  const float* bk = (const float*)d_in[5];
  const float* Wv = (const float*)d_in[6];
  const float* bv = (const float*)d_in[7];
  const float* Wo = (const float*)d_in[8];
  const float* bo = (const float*)d_in[9];
  const float* W1 = (const float*)d_in[10];
  const float* b1 = (const float*)d_in[11];
  const float* W2 = (const float*)d_in[12];
  const float* b2 = (const float*)d_in[13];

  float* out = (float*)d_out;
  float* attn = out + (size_t)BT * Dd;  // second output region

  const size_t QS = (size_t)Bc * Hh * Tt * Hd;  // 6291456
  float* ws = (float*)d_ws;
  float* q = ws;
  float* k = ws + QS;
  float* v = ws + 2 * QS;
  float* ff1 = ws + 3 * QS;
  float* ctx = q;  // reuse: q dead after scores
  float* h = k;    // reuse: k dead after scores

  dim3 blk(THREADS);

  // QKV projections -> split-head layout
  gemm128<0><<<dim3(6, 64), blk, 0, stream>>>(x, Wq, bq, nullptr, q, Dd, Dd);
  gemm128<0><<<dim3(6, 64), blk, 0, stream>>>(x, Wk, bk, nullptr, k, Dd, Dd);
  gemm128<0><<<dim3(6, 64), blk, 0, stream>>>(x, Wv, bv, nullptr, v, Dd, Dd);

  // attention scores + mask -> attn region of d_out
  scores_nt<<<dim3(16, 16, 48), blk, 0, stream>>>(q, k, mask, attn);

  // softmax in place (this IS the second output)
  softmax_rows<<<dim3(48 * 2048), blk, 0, stream>>>(attn);

  // ctx = attn @ V
  ctx_gemm<<<dim3(1, 16, 48), blk, 0, stream>>>(attn, v, ctx);

  // h = x + ctx @ Wo + bo
  gemm128<1><<<dim3(6, 64), blk, 0, stream>>>(ctx, Wo, bo, x, h, Dd, Dd);

  // ff1 = gelu(h @ W1 + b1)
  gemm128<2><<<dim3(24, 64), blk, 0, stream>>>(h, W1, b1, nullptr, ff1, Dd, Df);

  // out = h + ff1 @ W2 + b2
  gemm128<3><<<dim3(6, 64), blk, 0, stream>>>(ff1, W2, b2, h, out, Df, Dd);
}

// Round 2
// 1033.810 us; speedup vs baseline: 2.6029x; 2.6029x over previous
//
#include <hip/hip_runtime.h>
#include <hip/hip_bf16.h>
#include <math.h>

typedef unsigned short u16;
typedef __attribute__((ext_vector_type(8))) short short8;
typedef __attribute__((ext_vector_type(4))) float f32x4;

constexpr int Bc = 4, Tt = 2048, Dd = 768, Hh = 12, Hd = 64, Df = 3072;
constexpr int BT = Bc * Tt;  // 8192

__device__ __forceinline__ u16 f2b(float x) {
  __hip_bfloat16 h = __float2bfloat16(x);
  return *reinterpret_cast<u16*>(&h);
}
__device__ __forceinline__ float gelu_exact(float g) {
  return 0.5f * g * (1.0f + erff(g * 0.70710678118654752440f));
}
__device__ __forceinline__ void gload16(const void* g, void* l) {
  __builtin_amdgcn_global_load_lds(
      (const __attribute__((address_space(1))) unsigned int*)g,
      (__attribute__((address_space(3))) unsigned int*)l, 16, 0, 0);
}
__device__ __forceinline__ float waveMax(float v) {
#pragma unroll
  for (int o = 32; o; o >>= 1) v = fmaxf(v, __shfl_xor(v, o));
  return v;
}
__device__ __forceinline__ float waveSum(float v) {
#pragma unroll
  for (int o = 32; o; o >>= 1) v += __shfl_xor(v, o);
  return v;
}

// ---------------------------------------------------------------------------
// fp32 -> bf16 elementwise (n divisible by 8*256)
// ---------------------------------------------------------------------------
__global__ __launch_bounds__(256) void cvt_bf16(const float* __restrict__ in,
                                                u16* __restrict__ out, int n) {
  int i = (blockIdx.x * 256 + threadIdx.x) * 8;
  if (i >= n) return;
  float4 a = *(const float4*)&in[i];
  float4 b = *(const float4*)&in[i + 4];
  u16 t[8] = {f2b(a.x), f2b(a.y), f2b(a.z), f2b(a.w),
              f2b(b.x), f2b(b.y), f2b(b.z), f2b(b.w)};
  *(uint4*)&out[i] = *(uint4*)t;
}

// ---------------------------------------------------------------------------
// W [R][C] fp32 -> WT [C][R] bf16   (R,C multiples of 32)
// ---------------------------------------------------------------------------
__global__ __launch_bounds__(256) void tr_bf16(const float* __restrict__ in,
                                               u16* __restrict__ out, int R,
                                               int C) {
  __shared__ float sh[32][33];
  const int tx = threadIdx.x & 31, ty = threadIdx.x >> 5;
  const int r0 = blockIdx.y * 32, c0 = blockIdx.x * 32;
#pragma unroll
  for (int i = 0; i < 4; ++i)
    sh[ty + i * 8][tx] = in[(size_t)(r0 + ty + i * 8) * C + c0 + tx];
  __syncthreads();
#pragma unroll
  for (int i = 0; i < 4; ++i)
    out[(size_t)(c0 + ty + i * 8) * R + r0 + tx] = f2b(sh[tx][ty + i * 8]);
}

// ---------------------------------------------------------------------------
// bf16 MFMA NT GEMM, 128x128 tile, BK=32, 4 waves.
// A [M][K] bf16 row-major (MODE 2: gathered from split-head), Bt [N][K] bf16.
// MODE 0: C0 bf16 split-head [B,H,T,64]            (Q/K proj)
// MODE 1: C0 bf16 V-transposed [B,H,64,T]          (V proj)
// MODE 2: C0 fp32 h = add + acc + bias; C1 bf16 h  (Wo, A gathered)
// MODE 3: C0 bf16 gelu(acc + bias)                 (FF1)
// MODE 4: C0 fp32 add + acc + bias                 (FF2)
// ---------------------------------------------------------------------------
template <int MODE>
__global__ __launch_bounds__(256) void mgemm(
    const u16* __restrict__ A, const u16* __restrict__ Bt,
    const float* __restrict__ bias, const float* __restrict__ add,
    void* __restrict__ C0, void* __restrict__ C1, int K, int N) {
  __shared__ __align__(16) u16 As[128 * 32];
  __shared__ __align__(16) u16 Bs[128 * 32];
  const int tid = threadIdx.x;
  const int lane = tid & 63, wv = tid >> 6;
  const int m0 = blockIdx.y * 128, n0 = blockIdx.x * 128;
  const int wm = (wv >> 1) * 64, wn = (wv & 1) * 64;

  f32x4 acc[4][4] = {};

  for (int k0 = 0; k0 < K; k0 += 32) {
#pragma unroll
    for (int i = 0; i < 2; ++i) {
      const int idx = i * 256 + tid;  // wave-contiguous
      const int row = idx >> 2;
      const int kc = (idx & 3) * 8;
      const u16* ga;
      if constexpr (MODE == 2) {
        const int m = m0 + row, b = m >> 11, t = m & 2047;
        const int kk = k0 + kc, head = kk >> 6, d = kk & 63;
        ga = &A[(((size_t)(b * Hh + head) * Tt + t) << 6) + d];
      } else {
        ga = &A[(size_t)(m0 + row) * K + k0 + kc];
      }
      gload16(ga, &As[idx * 8]);
      gload16(&Bt[(size_t)(n0 + row) * K + k0 + kc], &Bs[idx * 8]);
    }
    __syncthreads();
    short8 af[4], bfr[4];
#pragma unroll
    for (int i = 0; i < 4; ++i) {
      af[i] = *reinterpret_cast<const short8*>(
          &As[(wm + i * 16 + (lane & 15)) * 32 + (lane >> 4) * 8]);
      bfr[i] = *reinterpret_cast<const short8*>(
          &Bs[(wn + i * 16 + (lane & 15)) * 32 + (lane >> 4) * 8]);
    }
#pragma unroll
    for (int i = 0; i < 4; ++i)
#pragma unroll
      for (int j = 0; j < 4; ++j)
        acc[i][j] = __builtin_amdgcn_mfma_f32_16x16x32_bf16(af[i], bfr[j],
                                                            acc[i][j], 0, 0, 0);
    __syncthreads();
  }

  const int lr = (lane >> 4) * 4, lc = lane & 15;
#pragma unroll
  for (int i = 0; i < 4; ++i) {
    const int mbase = m0 + wm + i * 16 + lr;
#pragma unroll
    for (int j = 0; j < 4; ++j) {
      const int col = n0 + wn + j * 16 + lc;
      const float bv = bias[col];
#pragma unroll
      for (int r = 0; r < 4; ++r) {
        const int m = mbase + r;
        float g = acc[i][j][r] + bv;
        if constexpr (MODE == 0) {
          const int b = m >> 11, t = m & 2047, head = col >> 6, d = col & 63;
          ((u16*)C0)[(((size_t)(b * Hh + head) * Tt + t) << 6) + d] = f2b(g);
        } else if constexpr (MODE == 1) {
          const int b = m >> 11, t = m & 2047, head = col >> 6, d = col & 63;
          ((u16*)C0)[(((size_t)(b * Hh + head) * Hd + d) << 11) + t] = f2b(g);
        } else if constexpr (MODE == 2) {
          g += add[(size_t)m * Dd + col];
          ((float*)C0)[(size_t)m * Dd + col] = g;
          ((u16*)C1)[(size_t)m * Dd + col] = f2b(g);
        } else if constexpr (MODE == 3) {
          ((u16*)C0)[(size_t)m * N + col] = f2b(gelu_exact(g));
        } else {
          g += add[(size_t)m * Dd + col];
          ((float*)C0)[(size_t)m * Dd + col] = g;
        }
      }
    }
  }
}

// ---------------------------------------------------------------------------
// scores = 0.125 * Q @ K^T per (b,h), mask==0 -> -inf, fp32 out.
// Q,K bf16 split-head [bh][2048][64].
// ---------------------------------------------------------------------------
__global__ __launch_bounds__(256) void scores_mfma(
    const u16* __restrict__ Q, const u16* __restrict__ Kh,
    const int* __restrict__ mask, float* __restrict__ attn) {
  const int bh = blockIdx.z;
  const u16* Qb = Q + (size_t)bh * Tt * Hd;
  const u16* Kb = Kh + (size_t)bh * Tt * Hd;
  float* Cb = attn + (size_t)bh * Tt * Tt;
  const int bb = bh / Hh;
  __shared__ __align__(16) u16 As[128 * 32];
  __shared__ __align__(16) u16 Bs[128 * 32];
  const int tid = threadIdx.x, lane = tid & 63, wv = tid >> 6;
  const int m0 = blockIdx.y * 128, n0 = blockIdx.x * 128;
  const int wm = (wv >> 1) * 64, wn = (wv & 1) * 64;
  f32x4 acc[4][4] = {};
#pragma unroll
  for (int k0 = 0; k0 < Hd; k0 += 32) {
#pragma unroll
    for (int i = 0; i < 2; ++i) {
      const int idx = i * 256 + tid;
      const int row = idx >> 2, kc = (idx & 3) * 8;
      gload16(&Qb[(size_t)(m0 + row) * Hd + k0 + kc], &As[idx * 8]);
      gload16(&Kb[(size_t)(n0 + row) * Hd + k0 + kc], &Bs[idx * 8]);
    }
    __syncthreads();
    short8 af[4], bfr[4];
#pragma unroll
    for (int i = 0; i < 4; ++i) {
      af[i] = *reinterpret_cast<const short8*>(
          &As[(wm + i * 16 + (lane & 15)) * 32 + (lane >> 4) * 8]);
      bfr[i] = *reinterpret_cast<const short8*>(
          &Bs[(wn + i * 16 + (lane & 15)) * 32 + (lane >> 4) * 8]);
    }
#pragma unroll
    for (int i = 0; i < 4; ++i)
#pragma unroll
      for (int j = 0; j < 4; ++j)
        acc[i][j] = __builtin_amdgcn_mfma_f32_16x16x32_bf16(af[i], bfr[j],
                                                            acc[i][j], 0, 0, 0);
    __syncthreads();
  }
  const int lr = (lane >> 4) * 4, lc = lane & 15;
#pragma unroll
  for (int i = 0; i < 4; ++i) {
#pragma unroll
    for (int j = 0; j < 4; ++j) {
      const int col = n0 + wn + j * 16 + lc;
      const bool dead = (mask[bb * Tt + col] == 0);
#pragma unroll
      for (int r = 0; r < 4; ++r) {
        const int m = m0 + wm + i * 16 + lr + r;
        float g = acc[i][j][r] * 0.125f;
        if (dead) g = -INFINITY;
        Cb[(size_t)m * Tt + col] = g;
      }
    }
  }
}

// ---------------------------------------------------------------------------
// Row softmax over 2048, in place, fp32.
// ---------------------------------------------------------------------------
__global__ __launch_bounds__(256) void softmax_rows(float* __restrict__ attn) {
  float* p = attn + (size_t)blockIdx.x * Tt;
  const int tid = threadIdx.x;
  float4 v0 = ((float4*)p)[tid];
  float4 v1 = ((float4*)p)[tid + 256];
  float x[8] = {v0.x, v0.y, v0.z, v0.w, v1.x, v1.y, v1.z, v1.w};

  float tmax = x[0];
#pragma unroll
  for (int i = 1; i < 8; i++) tmax = fmaxf(tmax, x[i]);
  tmax = waveMax(tmax);
  __shared__ float redm[4];
  if ((tid & 63) == 0) redm[tid >> 6] = tmax;
  __syncthreads();
  float bm = fmaxf(fmaxf(redm[0], redm[1]), fmaxf(redm[2], redm[3]));

  float tsum = 0.f;
#pragma unroll
  for (int i = 0; i < 8; i++) {
    x[i] = __expf(x[i] - bm);
    tsum += x[i];
  }
  tsum = waveSum(tsum);
  __shared__ float reds[4];
  if ((tid & 63) == 0) reds[tid >> 6] = tsum;
  __syncthreads();
  float bs = reds[0] + reds[1] + reds[2] + reds[3];
  float inv = 1.0f / bs;

  ((float4*)p)[tid] = make_float4(x[0] * inv, x[1] * inv, x[2] * inv, x[3] * inv);
  ((float4*)p)[tid + 256] =
      make_float4(x[4] * inv, x[5] * inv, x[6] * inv, x[7] * inv);
}

// ---------------------------------------------------------------------------
// ctx = attn @ V per (b,h).  attn fp32 (reg-staged to bf16 LDS),
// V given transposed bf16 [bh][64][2048].  Out ctx bf16 split-head.
// Tile 128(M) x 64(N), BK=32, 4 waves stacked on M (32 rows each).
// ---------------------------------------------------------------------------
__global__ __launch_bounds__(256) void ctx_mfma(const float* __restrict__ attn,
                                                const u16* __restrict__ VT,
                                                u16* __restrict__ ctxb) {
  const int bh = blockIdx.z;
  const float* Ab = attn + (size_t)bh * Tt * Tt;
  const u16* Vb = VT + (size_t)bh * Tt * Hd;  // [64][2048]
  u16* Cb = ctxb + (size_t)bh * Tt * Hd;      // [2048][64]
  __shared__ __align__(16) u16 As[128 * 32];
  __shared__ __align__(16) u16 Bs[64 * 32];
  const int tid = threadIdx.x, lane = tid & 63, wv = tid >> 6;
  const int m0 = blockIdx.y * 128;
  const int wm = wv * 32;
  f32x4 acc[2][4] = {};
  const int arow = tid >> 1, ahf = tid & 1;

  for (int k0 = 0; k0 < Tt; k0 += 32) {
    {  // stage A: fp32 -> bf16, 16 elems/thread
      const float* src = &Ab[(size_t)(m0 + arow) * Tt + k0 + ahf * 16];
      u16 tmp[16];
#pragma unroll
      for (int u = 0; u < 4; ++u) {
        float4 f = *(const float4*)&src[u * 4];
        tmp[u * 4 + 0] = f2b(f.x);
        tmp[u * 4 + 1] = f2b(f.y);
        tmp[u * 4 + 2] = f2b(f.z);
        tmp[u * 4 + 3] = f2b(f.w);
      }
      *(uint4*)&As[arow * 32 + ahf * 16] = *(uint4*)&tmp[0];
      *(uint4*)&As[arow * 32 + ahf * 16 + 8] = *(uint4*)&tmp[8];
    }
    gload16(&Vb[(size_t)(tid >> 2) * Tt + k0 + (tid & 3) * 8], &Bs[tid * 8]);
    __syncthreads();
    short8 af[2], bfr[4];
#pragma unroll
    for (int i = 0; i < 2; ++i)
      af[i] = *reinterpret_cast<const short8*>(
          &As[(wm + i * 16 + (lane & 15)) * 32 + (lane >> 4) * 8]);
#pragma unroll
    for (int j = 0; j < 4; ++j)
      bfr[j] = *reinterpret_cast<const short8*>(
          &Bs[(j * 16 + (lane & 15)) * 32 + (lane >> 4) * 8]);
#pragma unroll
    for (int i = 0; i < 2; ++i)
#pragma unroll
      for (int j = 0; j < 4; ++j)
        acc[i][j] = __builtin_amdgcn_mfma_f32_16x16x32_bf16(af[i], bfr[j],
                                                            acc[i][j], 0, 0, 0);
    __syncthreads();
  }
  const int lr = (lane >> 4) * 4, lc = lane & 15;
#pragma unroll
  for (int i = 0; i < 2; ++i)
#pragma unroll
    for (int j = 0; j < 4; ++j)
#pragma unroll
      for (int r = 0; r < 4; ++r) {
        const int trow = m0 + wm + i * 16 + lr + r;
        const int d = j * 16 + lc;
        Cb[(size_t)trow * Hd + d] = f2b(acc[i][j][r]);
      }
}

// ---------------------------------------------------------------------------
extern "C" void kernel_launch(void* const* d_in, const int* in_sizes, int n_in,
                              void* d_out, int out_size, void* d_ws,
                              size_t ws_size, hipStream_t stream) {
  const float* x = (const float*)d_in[0];
  const int* mask = (const int*)d_in[1];
  const float* Wq = (const float*)d_in[2];
  const float* bq = (const float*)d_in[3];
  const float* Wk = (const float*)d_in[4];
  const float* bk = (const float*)d_in[5];
  const float* Wv = (const float*)d_in[6];
  const float* bv = (const float*)d_in[7];
  const float* Wo = (const float*)d_in[8];
  const float* bo = (const float*)d_in[9];
  const float* W1 = (const float*)d_in[10];
  const float* b1 = (const float*)d_in[11];
  const float* W2 = (const float*)d_in[12];
  const float* b2 = (const float*)d_in[13];

  float* out = (float*)d_out;
  float* attn = out + (size_t)BT * Dd;

  char* w = (char*)d_ws;
  u16* xb = (u16*)w;    w += (size_t)BT * Dd * 2;
  u16* wqT = (u16*)w;   w += (size_t)Dd * Dd * 2;
  u16* wkT = (u16*)w;   w += (size_t)Dd * Dd * 2;
  u16* wvT = (u16*)w;   w += (size_t)Dd * Dd * 2;
  u16* woT = (u16*)w;   w += (size_t)Dd * Dd * 2;
  u16* w1T = (u16*)w;   w += (size_t)Dd * Df * 2;
  u16* w2T = (u16*)w;   w += (size_t)Df * Dd * 2;
  u16* qb = (u16*)w;    w += (size_t)BT * Dd * 2;
  u16* kb = (u16*)w;    w += (size_t)BT * Dd * 2;
  u16* vtb = (u16*)w;   w += (size_t)BT * Dd * 2;
  u16* ctxb = (u16*)w;  w += (size_t)BT * Dd * 2;
  u16* ff1b = (u16*)w;  w += (size_t)BT * Df * 2;
  float* h = (float*)qb;  // overlays qb+kb (dead after scores)
  u16* hb = vtb;          // overlays vtb (dead after ctx)

  dim3 blk(256);

  cvt_bf16<<<dim3(BT * Dd / (8 * 256)), blk, 0, stream>>>(x, xb, BT * Dd);
  tr_bf16<<<dim3(Dd / 32, Dd / 32), blk, 0, stream>>>(Wq, wqT, Dd, Dd);
  tr_bf16<<<dim3(Dd / 32, Dd / 32), blk, 0, stream>>>(Wk, wkT, Dd, Dd);
  tr_bf16<<<dim3(Dd / 32, Dd / 32), blk, 0, stream>>>(Wv, wvT, Dd, Dd);
  tr_bf16<<<dim3(Dd / 32, Dd / 32), blk, 0, stream>>>(Wo, woT, Dd, Dd);
  tr_bf16<<<dim3(Df / 32, Dd / 32), blk, 0, stream>>>(W1, w1T, Dd, Df);
  tr_bf16<<<dim3(Dd / 32, Df / 32), blk, 0, stream>>>(W2, w2T, Df, Dd);

  // QKV projections
  mgemm<0><<<dim3(6, 64), blk, 0, stream>>>(xb, wqT, bq, nullptr, qb, nullptr, Dd, Dd);
  mgemm<0><<<dim3(6, 64), blk, 0, stream>>>(xb, wkT, bk, nullptr, kb, nullptr, Dd, Dd);
  mgemm<1><<<dim3(6, 64), blk, 0, stream>>>(xb, wvT, bv, nullptr, vtb, nullptr, Dd, Dd);

  // attention
  scores_mfma<<<dim3(16, 16, 48), blk, 0, stream>>>(qb, kb, mask, attn);
  softmax_rows<<<dim3(48 * 2048), blk, 0, stream>>>(attn);
  ctx_mfma<<<dim3(1, 16, 48), blk, 0, stream>>>(attn, vtb, ctxb);

  // h = x + ctx@Wo + bo   (fp32 + bf16)
  mgemm<2><<<dim3(6, 64), blk, 0, stream>>>(ctxb, woT, bo, x, h, hb, Dd, Dd);

  // ff1 = gelu(h@W1 + b1) bf16
  mgemm<3><<<dim3(24, 64), blk, 0, stream>>>(hb, w1T, b1, nullptr, ff1b, nullptr, Dd, Df);

  // out = h + ff1@W2 + b2
  mgemm<4><<<dim3(6, 64), blk, 0, stream>>>(ff1b, w2T, b2, h, out, nullptr, Df, Dd);
}

// Round 3
// 636.222 us; speedup vs baseline: 4.2295x; 1.6249x over previous
//
#include <hip/hip_runtime.h>
#include <hip/hip_bf16.h>
#include <math.h>

typedef unsigned short u16;
typedef __attribute__((ext_vector_type(8))) short short8;
typedef __attribute__((ext_vector_type(4))) float f32x4;

constexpr int Bc = 4, Tt = 2048, Dd = 768, Hh = 12, Hd = 64, Df = 3072;
constexpr int BT = Bc * Tt;  // 8192

__device__ __forceinline__ u16 f2b(float x) {
  __hip_bfloat16 h = __float2bfloat16(x);
  return *reinterpret_cast<u16*>(&h);
}
__device__ __forceinline__ float gelu_exact(float g) {
  return 0.5f * g * (1.0f + erff(g * 0.70710678118654752440f));
}
__device__ __forceinline__ void gload16(const void* g, void* l) {
  __builtin_amdgcn_global_load_lds(
      (const __attribute__((address_space(1))) unsigned int*)g,
      (__attribute__((address_space(3))) unsigned int*)l, 16, 0, 0);
}

// ---------------------------------------------------------------------------
// fp32 -> bf16 elementwise
// ---------------------------------------------------------------------------
__global__ __launch_bounds__(256) void cvt_bf16(const float* __restrict__ in,
                                                u16* __restrict__ out, int n) {
  int i = (blockIdx.x * 256 + threadIdx.x) * 8;
  if (i >= n) return;
  float4 a = *(const float4*)&in[i];
  float4 b = *(const float4*)&in[i + 4];
  u16 t[8] = {f2b(a.x), f2b(a.y), f2b(a.z), f2b(a.w),
              f2b(b.x), f2b(b.y), f2b(b.z), f2b(b.w)};
  *(uint4*)&out[i] = *(uint4*)t;
}

// ---------------------------------------------------------------------------
// W [R][C] fp32 -> WT [C][R] bf16
// ---------------------------------------------------------------------------
__global__ __launch_bounds__(256) void tr_bf16(const float* __restrict__ in,
                                               u16* __restrict__ out, int R,
                                               int C) {
  __shared__ float sh[32][33];
  const int tx = threadIdx.x & 31, ty = threadIdx.x >> 5;
  const int r0 = blockIdx.y * 32, c0 = blockIdx.x * 32;
#pragma unroll
  for (int i = 0; i < 4; ++i)
    sh[ty + i * 8][tx] = in[(size_t)(r0 + ty + i * 8) * C + c0 + tx];
  __syncthreads();
#pragma unroll
  for (int i = 0; i < 4; ++i)
    out[(size_t)(c0 + ty + i * 8) * R + r0 + tx] = f2b(sh[tx][ty + i * 8]);
}

// ---------------------------------------------------------------------------
// biasc[2304] = bq|bk|bv ; maskf[8192] = mask ? 0 : -1e30
// ---------------------------------------------------------------------------
__global__ __launch_bounds__(256) void prep_small(
    const float* __restrict__ bq, const float* __restrict__ bk,
    const float* __restrict__ bv, const int* __restrict__ mask,
    float* __restrict__ biasc, float* __restrict__ maskf) {
  int i = blockIdx.x * 256 + threadIdx.x;
  if (i < 2304)
    biasc[i] = (i < 768) ? bq[i] : (i < 1536) ? bk[i - 768] : bv[i - 1536];
  int j = i - 2304;
  if (j >= 0 && j < Bc * Tt) maskf[j] = mask[j] ? 0.f : -1e30f;
}

// ---------------------------------------------------------------------------
// bf16 MFMA NT GEMM, 128x128 tile, BK=32, 4 waves.
// MODE 5: QKV fused (N=2304): cols 0-767 -> Q split-head, 768-1535 -> K
//         split-head, 1536-2303 -> V transposed [B,H,64,T]
// MODE 2: C0 fp32 h = add + acc + bias; C1 bf16 h  (Wo, A gathered split-head)
// MODE 3: C0 bf16 gelu(acc + bias)                 (FF1)
// MODE 4: C0 fp32 add + acc + bias                 (FF2)
// ---------------------------------------------------------------------------
template <int MODE>
__global__ __launch_bounds__(256) void mgemm(
    const u16* __restrict__ A, const u16* __restrict__ Bt,
    const float* __restrict__ bias, const float* __restrict__ add,
    void* __restrict__ C0, void* __restrict__ C1, void* __restrict__ C2,
    int K, int N) {
  __shared__ __align__(16) u16 As[128 * 32];
  __shared__ __align__(16) u16 Bs[128 * 32];
  const int tid = threadIdx.x;
  const int lane = tid & 63, wv = tid >> 6;
  const int m0 = blockIdx.y * 128, n0 = blockIdx.x * 128;
  const int wm = (wv >> 1) * 64, wn = (wv & 1) * 64;

  f32x4 acc[4][4] = {};

  for (int k0 = 0; k0 < K; k0 += 32) {
#pragma unroll
    for (int i = 0; i < 2; ++i) {
      const int idx = i * 256 + tid;
      const int row = idx >> 2;
      const int kc = (idx & 3) * 8;
      const u16* ga;
      if constexpr (MODE == 2) {
        const int m = m0 + row, b = m >> 11, t = m & 2047;
        const int kk = k0 + kc, head = kk >> 6, d = kk & 63;
        ga = &A[(((size_t)(b * Hh + head) * Tt + t) << 6) + d];
      } else {
        ga = &A[(size_t)(m0 + row) * K + k0 + kc];
      }
      gload16(ga, &As[idx * 8]);
      gload16(&Bt[(size_t)(n0 + row) * K + k0 + kc], &Bs[idx * 8]);
    }
    __syncthreads();
    short8 af[4], bfr[4];
#pragma unroll
    for (int i = 0; i < 4; ++i) {
      af[i] = *reinterpret_cast<const short8*>(
          &As[(wm + i * 16 + (lane & 15)) * 32 + (lane >> 4) * 8]);
      bfr[i] = *reinterpret_cast<const short8*>(
          &Bs[(wn + i * 16 + (lane & 15)) * 32 + (lane >> 4) * 8]);
    }
#pragma unroll
    for (int i = 0; i < 4; ++i)
#pragma unroll
      for (int j = 0; j < 4; ++j)
        acc[i][j] = __builtin_amdgcn_mfma_f32_16x16x32_bf16(af[i], bfr[j],
                                                            acc[i][j], 0, 0, 0);
    __syncthreads();
  }

  const int lr = (lane >> 4) * 4, lc = lane & 15;
#pragma unroll
  for (int i = 0; i < 4; ++i) {
    const int mbase = m0 + wm + i * 16 + lr;
#pragma unroll
    for (int j = 0; j < 4; ++j) {
      const int col = n0 + wn + j * 16 + lc;
      const float bvs = bias[col];
#pragma unroll
      for (int r = 0; r < 4; ++r) {
        const int m = mbase + r;
        float g = acc[i][j][r] + bvs;
        if constexpr (MODE == 5) {
          const int b = m >> 11, t = m & 2047;
          if (col < 768) {
            const int head = col >> 6, d = col & 63;
            ((u16*)C0)[(((size_t)(b * Hh + head) * Tt + t) << 6) + d] = f2b(g);
          } else if (col < 1536) {
            const int c = col - 768, head = c >> 6, d = c & 63;
            ((u16*)C1)[(((size_t)(b * Hh + head) * Tt + t) << 6) + d] = f2b(g);
          } else {
            const int c = col - 1536, head = c >> 6, d = c & 63;
            ((u16*)C2)[(((size_t)(b * Hh + head) * Hd + d) << 11) + t] = f2b(g);
          }
        } else if constexpr (MODE == 2) {
          g += add[(size_t)m * Dd + col];
          ((float*)C0)[(size_t)m * Dd + col] = g;
          ((u16*)C1)[(size_t)m * Dd + col] = f2b(g);
        } else if constexpr (MODE == 3) {
          ((u16*)C0)[(size_t)m * N + col] = f2b(gelu_exact(g));
        } else {
          g += add[(size_t)m * Dd + col];
          ((float*)C0)[(size_t)m * Dd + col] = g;
        }
      }
    }
  }
}

// ---------------------------------------------------------------------------
// Fused attention: scores -> softmax -> attn write (once) -> ctx, per
// (b,h, 128-q-row block).  Two passes over K tiles (QK^T recomputed).
// S^T = mfma(K, Q): acc col = q (lane&15), rows = kv -> softmax over kv is
// an in-thread + xor16/32 shuffle reduction, and P rows are kv-contiguous
// per thread -> ds_write_b64 into swizzled Ps, directly A-frag readable.
// LDS tiles XOR-swizzled via pre-swizzled global source (linear gload dest).
// ---------------------------------------------------------------------------
__global__ __launch_bounds__(256) void attn_fused(
    const u16* __restrict__ qb, const u16* __restrict__ kb,
    const u16* __restrict__ vtb, const float* __restrict__ maskf,
    float* __restrict__ attn, u16* __restrict__ ctxb) {
  const int bh = blockIdx.y;
  const int b = bh / Hh;
  const int q0 = blockIdx.x * 128;
  const u16* Qg = qb + (size_t)bh * Tt * Hd;
  const u16* Kg = kb + (size_t)bh * Tt * Hd;
  const u16* Vg = vtb + (size_t)bh * Hd * Tt;  // [64][2048]
  float* attng = attn + (size_t)bh * Tt * Tt;
  u16* ctxg = ctxb + (size_t)bh * Tt * Hd;
  const float* mfp = maskf + b * Tt;

  __shared__ __align__(16) u16 Qs[128 * 64];
  __shared__ __align__(16) u16 Ks[128 * 64];
  __shared__ __align__(16) u16 Vs[64 * 128];
  __shared__ __align__(16) u16 Ps[128 * 128];
  __shared__ __align__(16) float Ms[128];

  const int tid = threadIdx.x, lane = tid & 63, wv = tid >> 6;
  const int lc = lane & 15, lg = lane >> 4;

  // stage Q once (pre-swizzled source, linear dest)
#pragma unroll
  for (int w = 0; w < 4; ++w) {
    int p = w * 256 + tid;
    int row = p >> 3, kc8 = (p & 7) ^ (row & 7);
    gload16(Qg + (size_t)(q0 + row) * Hd + kc8 * 8, &Qs[p * 8]);
  }

  float m[2] = {-1e30f, -1e30f}, l[2] = {0.f, 0.f};

  // ---------------- pass 1: running m, l ----------------
  for (int t = 0; t < 16; ++t) {
    const int kv0 = t * 128;
#pragma unroll
    for (int w = 0; w < 4; ++w) {
      int p = w * 256 + tid;
      int row = p >> 3, kc8 = (p & 7) ^ (row & 7);
      gload16(Kg + (size_t)(kv0 + row) * Hd + kc8 * 8, &Ks[p * 8]);
    }
    if (tid < 32) *(float4*)&Ms[tid * 4] = *(const float4*)&mfp[kv0 + tid * 4];
    __syncthreads();

    f32x4 s[8][2] = {};
#pragma unroll
    for (int ks = 0; ks < 2; ++ks) {
      short8 af[8], bf2[2];
#pragma unroll
      for (int i = 0; i < 8; ++i) {
        int row = i * 16 + lc;
        int ph = (ks * 4 + lg) ^ (row & 7);
        af[i] = *(const short8*)&Ks[row * 64 + ph * 8];
      }
#pragma unroll
      for (int j = 0; j < 2; ++j) {
        int qr = wv * 32 + j * 16 + lc;
        int ph = (ks * 4 + lg) ^ (qr & 7);
        bf2[j] = *(const short8*)&Qs[qr * 64 + ph * 8];
      }
#pragma unroll
      for (int i = 0; i < 8; ++i)
#pragma unroll
        for (int j = 0; j < 2; ++j)
          s[i][j] = __builtin_amdgcn_mfma_f32_16x16x32_bf16(af[i], bf2[j],
                                                            s[i][j], 0, 0, 0);
    }
    float mv[8][4];
#pragma unroll
    for (int i = 0; i < 8; ++i) {
      float4 mm = *(const float4*)&Ms[i * 16 + lg * 4];
      mv[i][0] = mm.x; mv[i][1] = mm.y; mv[i][2] = mm.z; mv[i][3] = mm.w;
    }
#pragma unroll
    for (int j = 0; j < 2; ++j) {
      float tm = -1e30f;
#pragma unroll
      for (int i = 0; i < 8; ++i)
#pragma unroll
        for (int r = 0; r < 4; ++r) {
          float v = s[i][j][r] * 0.125f + mv[i][r];
          s[i][j][r] = v;
          tm = fmaxf(tm, v);
        }
      tm = fmaxf(tm, __shfl_xor(tm, 16));
      tm = fmaxf(tm, __shfl_xor(tm, 32));
      float mn = fmaxf(m[j], tm);
      float ts = 0.f;
#pragma unroll
      for (int i = 0; i < 8; ++i)
#pragma unroll
        for (int r = 0; r < 4; ++r) ts += __expf(s[i][j][r] - mn);
      ts += __shfl_xor(ts, 16);
      ts += __shfl_xor(ts, 32);
      l[j] = l[j] * __expf(m[j] - mn) + ts;
      m[j] = mn;
    }
    __syncthreads();
  }

  const float linv[2] = {1.f / l[0], 1.f / l[1]};
  f32x4 cacc[2][4] = {};

  // ---------------- pass 2: P write + ctx ----------------
  for (int t = 0; t < 16; ++t) {
    const int kv0 = t * 128;
#pragma unroll
    for (int w = 0; w < 4; ++w) {
      int p = w * 256 + tid;
      int row = p >> 3, kc8 = (p & 7) ^ (row & 7);
      gload16(Kg + (size_t)(kv0 + row) * Hd + kc8 * 8, &Ks[p * 8]);
    }
#pragma unroll
    for (int w = 0; w < 4; ++w) {
      int p = w * 256 + tid;
      int d = p >> 4, pc = (p & 15) ^ (d & 7);
      gload16(Vg + (size_t)d * Tt + kv0 + pc * 8, &Vs[p * 8]);
    }
    if (tid < 32) *(float4*)&Ms[tid * 4] = *(const float4*)&mfp[kv0 + tid * 4];
    __syncthreads();

    f32x4 s[8][2] = {};
#pragma unroll
    for (int ks = 0; ks < 2; ++ks) {
      short8 af[8], bf2[2];
#pragma unroll
      for (int i = 0; i < 8; ++i) {
        int row = i * 16 + lc;
        int ph = (ks * 4 + lg) ^ (row & 7);
        af[i] = *(const short8*)&Ks[row * 64 + ph * 8];
      }
#pragma unroll
      for (int j = 0; j < 2; ++j) {
        int qr = wv * 32 + j * 16 + lc;
        int ph = (ks * 4 + lg) ^ (qr & 7);
        bf2[j] = *(const short8*)&Qs[qr * 64 + ph * 8];
      }
#pragma unroll
      for (int i = 0; i < 8; ++i)
#pragma unroll
        for (int j = 0; j < 2; ++j)
          s[i][j] = __builtin_amdgcn_mfma_f32_16x16x32_bf16(af[i], bf2[j],
                                                            s[i][j], 0, 0, 0);
    }
#pragma unroll
    for (int j = 0; j < 2; ++j) {
      const int ql = wv * 32 + j * 16 + lc;  // local q row
#pragma unroll
      for (int i = 0; i < 8; ++i) {
        float4 mm = *(const float4*)&Ms[i * 16 + lg * 4];
        float pv[4];
        u16 pb[4];
#pragma unroll
        for (int r = 0; r < 4; ++r) {
          float v = s[i][j][r] * 0.125f + ((const float*)&mm)[r];
          float p = __expf(v - m[j]) * linv[j];
          pv[r] = p;
          pb[r] = f2b(p);
        }
        *(float4*)&attng[(size_t)(q0 + ql) * Tt + kv0 + i * 16 + lg * 4] =
            make_float4(pv[0], pv[1], pv[2], pv[3]);
        const int chunk = i * 2 + (lg >> 1);
        const int ph = chunk ^ (ql & 7);
        *(uint2*)&Ps[ql * 128 + ph * 8 + (lg & 1) * 4] = *(uint2*)pb;
      }
    }
    __syncthreads();

    // ctx += P @ V^T-tile
#pragma unroll
    for (int ks = 0; ks < 4; ++ks) {
      short8 pa[2], vb2[4];
#pragma unroll
      for (int i2 = 0; i2 < 2; ++i2) {
        int qr = wv * 32 + i2 * 16 + lc;
        int ph = (ks * 4 + lg) ^ (qr & 7);
        pa[i2] = *(const short8*)&Ps[qr * 128 + ph * 8];
      }
#pragma unroll
      for (int j2 = 0; j2 < 4; ++j2) {
        int d = j2 * 16 + lc;
        int ph = (ks * 4 + lg) ^ (d & 7);
        vb2[j2] = *(const short8*)&Vs[d * 128 + ph * 8];
      }
#pragma unroll
      for (int i2 = 0; i2 < 2; ++i2)
#pragma unroll
        for (int j2 = 0; j2 < 4; ++j2)
          cacc[i2][j2] = __builtin_amdgcn_mfma_f32_16x16x32_bf16(
              pa[i2], vb2[j2], cacc[i2][j2], 0, 0, 0);
    }
    __syncthreads();
  }

  // ctx epilogue: rows q, cols d, bf16 split-head
#pragma unroll
  for (int i2 = 0; i2 < 2; ++i2)
#pragma unroll
    for (int j2 = 0; j2 < 4; ++j2)
#pragma unroll
      for (int r = 0; r < 4; ++r) {
        const int q = q0 + wv * 32 + i2 * 16 + lg * 4 + r;
        const int d = j2 * 16 + lc;
        ctxg[(size_t)q * Hd + d] = f2b(cacc[i2][j2][r]);
      }
}

// ---------------------------------------------------------------------------
extern "C" void kernel_launch(void* const* d_in, const int* in_sizes, int n_in,
                              void* d_out, int out_size, void* d_ws,
                              size_t ws_size, hipStream_t stream) {
  const float* x = (const float*)d_in[0];
  const int* mask = (const int*)d_in[1];
  const float* Wq = (const float*)d_in[2];
  const float* bq = (const float*)d_in[3];
  const float* Wk = (const float*)d_in[4];
  const float* bk = (const float*)d_in[5];
  const float* Wv = (const float*)d_in[6];
  const float* bv = (const float*)d_in[7];
  const float* Wo = (const float*)d_in[8];
  const float* bo = (const float*)d_in[9];
  const float* W1 = (const float*)d_in[10];
  const float* b1 = (const float*)d_in[11];
  const float* W2 = (const float*)d_in[12];
  const float* b2 = (const float*)d_in[13];

  float* out = (float*)d_out;
  float* attn = out + (size_t)BT * Dd;

  char* w = (char*)d_ws;
  u16* xb = (u16*)w;      w += (size_t)BT * Dd * 2;
  u16* wqkvT = (u16*)w;   w += (size_t)Dd * 2304 * 2;
  u16* woT = (u16*)w;     w += (size_t)Dd * Dd * 2;
  u16* w1T = (u16*)w;     w += (size_t)Dd * Df * 2;
  u16* w2T = (u16*)w;     w += (size_t)Df * Dd * 2;
  float* biasc = (float*)w; w += 2304 * 4;
  float* maskf = (float*)w; w += (size_t)BT * 4;
  u16* qb = (u16*)w;      w += (size_t)BT * Dd * 2;
  u16* kb = (u16*)w;      w += (size_t)BT * Dd * 2;
  u16* vtb = (u16*)w;     w += (size_t)BT * Dd * 2;
  u16* ctxb = (u16*)w;    w += (size_t)BT * Dd * 2;
  u16* ff1b = (u16*)w;    w += (size_t)BT * Df * 2;
  float* h = (float*)qb;  // overlays qb+kb (dead after attn_fused)
  u16* hb = vtb;          // overlays vtb (dead after attn_fused)

  dim3 blk(256);

  cvt_bf16<<<dim3(BT * Dd / (8 * 256)), blk, 0, stream>>>(x, xb, BT * Dd);
  tr_bf16<<<dim3(Dd / 32, Dd / 32), blk, 0, stream>>>(Wq, wqkvT, Dd, Dd);
  tr_bf16<<<dim3(Dd / 32, Dd / 32), blk, 0, stream>>>(Wk, wqkvT + 768 * Dd, Dd, Dd);
  tr_bf16<<<dim3(Dd / 32, Dd / 32), blk, 0, stream>>>(Wv, wqkvT + 1536 * Dd, Dd, Dd);
  tr_bf16<<<dim3(Dd / 32, Dd / 32), blk, 0, stream>>>(Wo, woT, Dd, Dd);
  tr_bf16<<<dim3(Df / 32, Dd / 32), blk, 0, stream>>>(W1, w1T, Dd, Df);
  tr_bf16<<<dim3(Dd / 32, Df / 32), blk, 0, stream>>>(W2, w2T, Df, Dd);
  prep_small<<<dim3(41), blk, 0, stream>>>(bq, bk, bv, mask, biasc, maskf);

  // fused QKV projection (N = 2304)
  mgemm<5><<<dim3(18, 64), blk, 0, stream>>>(xb, wqkvT, biasc, nullptr, qb, kb,
                                             vtb, Dd, 2304);

  // fused attention: attn (written once) + ctx
  attn_fused<<<dim3(16, 48), blk, 0, stream>>>(qb, kb, vtb, maskf, attn, ctxb);

  // h = x + ctx@Wo + bo   (fp32 + bf16)
  mgemm<2><<<dim3(6, 64), blk, 0, stream>>>(ctxb, woT, bo, x, h, hb, nullptr,
                                            Dd, Dd);

  // ff1 = gelu(h@W1 + b1) bf16
  mgemm<3><<<dim3(24, 64), blk, 0, stream>>>(hb, w1T, b1, nullptr, ff1b,
                                             nullptr, nullptr, Dd, Df);

  // out = h + ff1@W2 + b2
  mgemm<4><<<dim3(6, 64), blk, 0, stream>>>(ff1b, w2T, b2, h, out, nullptr,
                                            nullptr, Df, Dd);
}